// Round 18
// baseline (1209.239 us; speedup 1.0000x reference)
//
#include <hip/hip_runtime.h>
#include <hip/hip_fp16.h>

#define N_NODES 20000
#define N_EDGES 320000
#define BATCH   64
#define N_IN    128
#define N_OUT   256
#define CAP     64
#define ITERS   150
#define LEAK    0.01f

#define CNT_MASK 0x3FFFFFFF
#define FLAG_BIT (1 << 30)

#define NSLICE 32          // batch pairs; slice s owns batch elems {2s,2s+1}
#define BPS    8           // blocks per slice
#define NPB    2500        // ranks per block-chunk
#define NT     1024        // threads per block
#define NBLK   (NSLICE * BPS)
#define SLICE_U32 20480    // padded slice stride (u32)
#define OWN_U128  625      // NPB/4 uint4 per sub-block
#define PAIRS  32          // edge-pair slots per node (CAP/2)
#define TAG_STRIDE 32      // uints -> 128 B between tags

typedef unsigned int uint;
typedef unsigned long long ull;
typedef _Float16 h2_t __attribute__((ext_vector_type(2)));
typedef uint u32x4 __attribute__((ext_vector_type(4)));

// MALL-coherent accessors — RELAXED sc0 sc1 ONLY (L1+L2 bypass; Infinity-
// Cache-coherent). Proven protocol (r9/10/11/14/15/17). acquire/release
// (whole-L2 inv/wb) and the XCD-L2 exchange path (hangs r13/r16) are banned.
__device__ __forceinline__ void st32_mall(uint* p, uint v) {
    asm volatile("global_store_dword %0, %1, off sc0 sc1"
                 :: "v"(p), "v"(v) : "memory");
}
__device__ __forceinline__ uint ld32_mall(const uint* p) {
    uint v;
    asm volatile("global_load_dword %0, %1, off sc0 sc1\n\t"
                 "s_waitcnt vmcnt(0)"
                 : "=v"(v) : "v"(p) : "memory");
    return v;
}

__device__ __forceinline__ float fdot2u(uint w, uint h, float acc) {
    union { uint u; h2_t h; } a, b; a.u = w; b.u = h;
    return __builtin_amdgcn_fdot2(a.h, b.h, acc, false);
}

// ---------------------------------------------------------------------------
// setup: zero both h buffers (incl. padding), cnt, meta, tags
// ---------------------------------------------------------------------------
__global__ void setup_kernel(uint* __restrict__ hGA, uint* __restrict__ hGB,
                             int* __restrict__ cnt,
                             uint* __restrict__ colpair, uint* __restrict__ wpair,
                             uint* __restrict__ tags) {
    int idx = blockIdx.x * blockDim.x + threadIdx.x;
    int stride = gridDim.x * blockDim.x;
    for (int i = idx; i < NSLICE * SLICE_U32; i += stride) { hGA[i] = 0u; hGB[i] = 0u; }
    for (int i = idx; i < N_NODES; i += stride) cnt[i] = 0;
    for (int i = idx; i < PAIRS * N_NODES; i += stride) { colpair[i] = 0u; wpair[i] = 0u; }
    for (int i = idx; i < NSLICE * BPS * TAG_STRIDE; i += stride) tags[i] = 0u;
}

// ---------------------------------------------------------------------------
// input scatter: bin[in_idx[i]][b] = bias + in_w[i]*x[b][i], last-wins.
// Flags the node (bit 30 of cnt).
// ---------------------------------------------------------------------------
__global__ void input_scatter_kernel(float* __restrict__ bin,
                                     const float* __restrict__ x,
                                     const float* __restrict__ in_w,
                                     const int* __restrict__ in_idx,
                                     const float* __restrict__ biases,
                                     int* __restrict__ cnt) {
    int i = blockIdx.x;
    int b = threadIdx.x;
    int node = in_idx[i];
    if (b == 0) atomicOr(&cnt[node], FLAG_BIT);
    for (int j = i + 1; j < N_IN; j++)
        if (in_idx[j] == node) return;
    bin[node * BATCH + b] = biases[node] + in_w[i] * x[b * N_IN + i];
}

// ---------------------------------------------------------------------------
// COO -> paired transposed ELL in NODE space (atomicOr into 16-bit subwords)
// ---------------------------------------------------------------------------
__global__ void ell_build_kernel(const int* __restrict__ rows,
                                 const int* __restrict__ cols,
                                 const float* __restrict__ rec_w,
                                 uint* __restrict__ colpair, uint* __restrict__ wpair,
                                 int* __restrict__ cnt) {
    int e = blockIdx.x * blockDim.x + threadIdx.x;
    if (e >= N_EDGES) return;
    int r = rows[e];
    int s = atomicAdd(&cnt[r], 1) & CNT_MASK;
    if (s < CAP) {
        int p = s >> 1, sh = (s & 1) * 16;
        atomicOr(&colpair[(size_t)p * N_NODES + r], (uint)cols[e] << sh);
        uint hw = (uint)__half_as_ushort(__float2half(rec_w[e]));
        atomicOr(&wpair[(size_t)p * N_NODES + r], hw << sh);
    }
}

// ---------------------------------------------------------------------------
// per-chunk descending counting sort by degree.
// ---------------------------------------------------------------------------
__global__ __launch_bounds__(NT) void sort_kernel(const int* __restrict__ cnt,
                                                  int* __restrict__ permG,
                                                  int* __restrict__ rankOf) {
    __shared__ int hist[65], off[65];
    int nbase = blockIdx.x * NPB;
    int tid = threadIdx.x;
    if (tid < 65) hist[tid] = 0;
    __syncthreads();
    for (int r = tid; r < NPB; r += NT) {
        int c = cnt[nbase + r] & CNT_MASK; if (c > CAP) c = CAP;
        atomicAdd(&hist[c], 1);
    }
    __syncthreads();
    if (tid == 0) {
        int run = 0;
        for (int c = CAP; c >= 0; c--) { off[c] = run; run += hist[c]; }
    }
    __syncthreads();
    for (int r = tid; r < NPB; r += NT) {
        int c = cnt[nbase + r] & CNT_MASK; if (c > CAP) c = CAP;
        int rk = atomicAdd(&off[c], 1);
        permG[nbase + rk] = nbase + r;
        rankOf[nbase + r] = nbase + rk;
    }
}

// reorder meta into RANK space, remap columns, merge into one uint2
__global__ void reorder_kernel(const uint* __restrict__ colpair,
                               const uint* __restrict__ wpair,
                               const int* __restrict__ permG,
                               const int* __restrict__ rankOf,
                               uint2* __restrict__ cwR) {
    int r = blockIdx.x * blockDim.x + threadIdx.x;
    int p = blockIdx.y;
    if (r >= N_NODES) return;
    size_t o = (size_t)p * N_NODES;
    int n = permG[r];
    uint cc = colpair[o + n];
    uint lo = (uint)rankOf[cc & 0xFFFFu];
    uint hi = (uint)rankOf[cc >> 16];
    cwR[o + r] = make_uint2(lo | (hi << 16), wpair[o + n]);
}

// ---------------------------------------------------------------------------
// shared pieces
// ---------------------------------------------------------------------------
__device__ __forceinline__ uint finish_node(float a0, float a1, float b0, float b1) {
    float r0 = b0 + a0, r1 = b1 + a1;
    float u0 = (r0 < 0.f) ? r0 * LEAK : r0;
    float u1 = (r1 < 0.f) ? r1 * LEAK : r1;
    float v0 = (u0 > 0.5f) ? (1.0f - 0.25f / u0) : u0;
    float v1 = (u1 > 0.5f) ? (1.0f - 0.25f / u1) : u1;
    union { __half2 h; uint u; } p;
    p.h = __halves2half2(__float2half(v0), __float2half(v1));
    return p.u;
}

__device__ __forceinline__ void hoist_consts(
        int nbase, int tid, int s,
        const int* __restrict__ cnt, const int* __restrict__ permG,
        const float* __restrict__ bin, const float* __restrict__ biases,
        int* rank, float* mb0, float* mb1, bool* ma, int& kp) {
    int kmax = 0;
#pragma unroll
    for (int j = 0; j < 3; j++) {
        int sl = 3 * tid + j;
        ma[j] = (sl < NPB);
        rank[j] = nbase + (ma[j] ? sl : 0);
        int n = permG[rank[j]];
        int cv = cnt[n];
        int c = cv & CNT_MASK; if (c > CAP) c = CAP;
        if (ma[j] && c > kmax) kmax = c;
        if (cv & FLAG_BIT) {
            mb0[j] = bin[(size_t)n * BATCH + 2 * s];
            mb1[j] = bin[(size_t)n * BATCH + 2 * s + 1];
        } else {
            float bb = biases[n]; mb0[j] = bb; mb1[j] = bb;
        }
    }
    kp = (kmax + 1) >> 1;
}

// 3 rank streams x paired edges: 6 independent ds_reads/iter, fdot2 accum.
__device__ __forceinline__ void compute_pairs(
        const int* rank, int kp,
        const uint2* __restrict__ cwR,
        const uint* __restrict__ lds_h, float* a0, float* a1) {
    a0[0] = a0[1] = a0[2] = 0.f;
    a1[0] = a1[1] = a1[2] = 0.f;
#pragma unroll 2
    for (int p = 0; p < kp; p++) {
        size_t o = (size_t)p * N_NODES;
#pragma unroll
        for (int j = 0; j < 3; j++) {
            uint2 m = cwR[o + rank[j]];
            uint ha = lds_h[m.x & 0xFFFFu];
            uint hb = lds_h[m.x >> 16];
            uint lo = __builtin_amdgcn_perm(hb, ha, 0x05040100u);
            uint hi = __builtin_amdgcn_perm(hb, ha, 0x07060302u);
            a0[j] = fdot2u(m.y, lo, a0[j]);
            a1[j] = fdot2u(m.y, hi, a1[j]);
        }
    }
}

// ---------------------------------------------------------------------------
// persistent kernel: DOUBLE-BUFFERED LDS (2 x 80 KB = full CU LDS).
// Per step (2 barriers, publish/refresh overlapped):
//   compute from cur -> write own v to nxt (different buffer: race-free,
//   no barrier) + publish v from REGISTERS (3 dword sc0sc1 stores/thread)
//   -> sync (drains all publish stores) -> tid0 writes tag (r17 protocol)
//   while waves 0..13 poll remote tags and refresh nxt's remote sub-ranges
//   -> sync -> swap(cur,nxt).
// Same monotone-tag / 2-buffer invariant r17 proved; no protocol selection.
// ---------------------------------------------------------------------------
__global__ __launch_bounds__(NT) void persistent_kernel(
        uint* hGA, uint* hGB,
        const float* __restrict__ bin, const float* __restrict__ biases,
        const uint2* __restrict__ cwR,
        const int* __restrict__ cnt, const int* __restrict__ permG,
        uint* tags) {
    extern __shared__ uint lds_all[];        // 2 x SLICE_U32 = 160 KB
    uint* bufA = lds_all;
    uint* bufB = lds_all + SLICE_U32;
    int bid = blockIdx.x, tid = threadIdx.x;
    int s = bid >> 3, sub = bid & 7;
    int nbase = sub * NPB;
    const int wave = tid >> 6, lane = tid & 63;

    int rank[3]; float mb0[3], mb1[3]; bool ma[3]; int kp;
    hoist_consts(nbase, tid, s, cnt, permG, bin, biases, rank, mb0, mb1, ma, kp);

    for (int i = tid; i < SLICE_U32; i += NT) bufA[i] = 0u;   // h_{-1} = 0
    __syncthreads();

    uint* hA_s = hGA + (size_t)s * SLICE_U32;
    uint* hB_s = hGB + (size_t)s * SLICE_U32;
    uint* mytag = &tags[(s * BPS + sub) * TAG_STRIDE];

    uint* cur = bufA;
    uint* nxt = bufB;

    for (int t = 0; t < ITERS; t++) {
        uint* hout = (t & 1) ? hB_s : hA_s;

        float a0[3], a1[3];
        compute_pairs(rank, kp, cwR, cur, a0, a1);
        // own-write to nxt (no race: compute reads cur) + publish from regs
#pragma unroll
        for (int j = 0; j < 3; j++) {
            if (ma[j]) {
                uint v = finish_node(a0[j], a1[j], mb0[j], mb1[j]);
                nxt[rank[j]] = v;
                st32_mall(&hout[rank[j]], v);
            }
        }
        if (t == ITERS - 1) break;

        __syncthreads();            // all publish stores drained (vmcnt0), all
                                    // compute reads of cur done
        if (tid == 0) st32_mall(mytag, (uint)(t + 1));

        // refresh nxt's remote sub-ranges (waves 0..13; 2 waves per range)
        if (wave < 14) {
            int sb_idx = wave >> 1;
            int sb = sb_idx + (sb_idx >= sub ? 1 : 0);
            int half = wave & 1;
            if (lane == 0) {
                const uint* rt = &tags[(s * BPS + sb) * TAG_STRIDE];
                while (ld32_mall(rt) < (uint)(t + 1)) __builtin_amdgcn_s_sleep(2);
            }
            // wave reconverged: 2 waves cover this sub-range's 625 uint4
            const u32x4* sp = (const u32x4*)hout + sb * OWN_U128;
            u32x4* dp = (u32x4*)nxt + sb * OWN_U128;
            int it0 = half * 64 + lane;          // 0..127
            int it4 = it0 + 512;                 // 512..639 (guard > 624)
            int c4 = (it4 <= 624) ? it4 : 624;
            u32x4 r0, r1, r2, r3, r4;
            asm volatile(
                "global_load_dwordx4 %0, %5, off sc0 sc1\n\t"
                "global_load_dwordx4 %1, %6, off sc0 sc1\n\t"
                "global_load_dwordx4 %2, %7, off sc0 sc1\n\t"
                "global_load_dwordx4 %3, %8, off sc0 sc1\n\t"
                "global_load_dwordx4 %4, %9, off sc0 sc1\n\t"
                "s_waitcnt vmcnt(0)"
                : "=&v"(r0), "=&v"(r1), "=&v"(r2), "=&v"(r3), "=&v"(r4)
                : "v"(sp + it0), "v"(sp + it0 + 128), "v"(sp + it0 + 256),
                  "v"(sp + it0 + 384), "v"(sp + c4)
                : "memory");
            dp[it0] = r0; dp[it0 + 128] = r1; dp[it0 + 256] = r2;
            dp[it0 + 384] = r3;
            if (it4 <= 624) dp[it4] = r4;
        }
        __syncthreads();            // refresh + own-writes visible
        uint* tmp = cur; cur = nxt; nxt = tmp;
    }
}

// ---------------------------------------------------------------------------
// fallback: one step per launch (dispatch boundary = sync), 80 KB LDS,
// byte-identical numerics (r17-proven)
// ---------------------------------------------------------------------------
__global__ __launch_bounds__(NT) void step_kernel(
        const uint* __restrict__ hprev, uint* __restrict__ hnext,
        const float* __restrict__ bin, const float* __restrict__ biases,
        const uint2* __restrict__ cwR,
        const int* __restrict__ cnt, const int* __restrict__ permG) {
    extern __shared__ uint lds_h[];
    int bid = blockIdx.x, tid = threadIdx.x;
    int s = bid >> 3, sub = bid & 7;
    int nbase = sub * NPB;

    int rank[3]; float mb0[3], mb1[3]; bool ma[3]; int kp;
    hoist_consts(nbase, tid, s, cnt, permG, bin, biases, rank, mb0, mb1, ma, kp);

    const uint* hp = hprev + (size_t)s * SLICE_U32;
    for (int i = tid; i < SLICE_U32; i += NT) lds_h[i] = hp[i];
    __syncthreads();

    float a0[3], a1[3];
    compute_pairs(rank, kp, cwR, lds_h, a0, a1);
    uint* ho = hnext + (size_t)s * SLICE_U32;
#pragma unroll
    for (int j = 0; j < 3; j++)
        if (ma[j]) ho[rank[j]] = finish_node(a0[j], a1[j], mb0[j], mb1[j]);
}

// ---------------------------------------------------------------------------
// output gather: out[b][o] = out_w[o] * h[rankOf[out_idx[o]]][b]
// ---------------------------------------------------------------------------
__global__ void output_kernel(const uint* __restrict__ hfinal,
                              const int* __restrict__ out_idx,
                              const int* __restrict__ rankOf,
                              const float* __restrict__ out_w,
                              float* __restrict__ out) {
    int o = threadIdx.x;
    int b = blockIdx.x;
    uint v = hfinal[(size_t)(b >> 1) * SLICE_U32 + rankOf[out_idx[o]]];
    unsigned short h = (b & 1) ? (unsigned short)(v >> 16) : (unsigned short)(v & 0xFFFF);
    out[b * N_OUT + o] = out_w[o] * __half2float(__ushort_as_half(h));
}

// ---------------------------------------------------------------------------
extern "C" void kernel_launch(void* const* d_in, const int* in_sizes, int n_in,
                              void* d_out, int out_size, void* d_ws, size_t ws_size,
                              hipStream_t stream) {
    const float* x      = (const float*)d_in[0];
    const float* in_w   = (const float*)d_in[1];
    const float* out_w  = (const float*)d_in[2];
    const float* rec_w  = (const float*)d_in[3];
    const float* biases = (const float*)d_in[4];
    const int*   rows   = (const int*)d_in[5];
    const int*   cols   = (const int*)d_in[6];
    const int*   in_idx = (const int*)d_in[7];
    const int*   oidx   = (const int*)d_in[8];
    float* out = (float*)d_out;

    char* ws = (char*)d_ws;
    uint*  hGA     = (uint*)ws;  ws += (size_t)NSLICE * SLICE_U32 * 4;  // 2.62 MB
    uint*  hGB     = (uint*)ws;  ws += (size_t)NSLICE * SLICE_U32 * 4;  // 2.62 MB
    float* bin     = (float*)ws; ws += (size_t)N_NODES * BATCH * 4;     // 5.12 MB
    uint*  colpair = (uint*)ws;  ws += (size_t)PAIRS * N_NODES * 4;     // 2.56 MB
    uint*  wpair   = (uint*)ws;  ws += (size_t)PAIRS * N_NODES * 4;     // 2.56 MB
    uint2* cwR     = (uint2*)ws; ws += (size_t)PAIRS * N_NODES * 8;     // 5.12 MB
    int*   cnt     = (int*)ws;   ws += (size_t)N_NODES * 4;             // 80 KB
    int*   permG   = (int*)ws;   ws += (size_t)N_NODES * 4;             // 80 KB
    int*   rankOf  = (int*)ws;   ws += (size_t)N_NODES * 4;             // 80 KB
    uint*  tags    = (uint*)ws;  ws += (size_t)NSLICE * BPS * TAG_STRIDE * 4;

    const int shmem_p = 2 * SLICE_U32 * 4;   // 163840 B (full CU LDS)
    const int shmem_f = SLICE_U32 * 4;       // 81920 B (fallback)
    hipFuncSetAttribute((const void*)persistent_kernel,
                        hipFuncAttributeMaxDynamicSharedMemorySize, shmem_p);
    hipFuncSetAttribute((const void*)step_kernel,
                        hipFuncAttributeMaxDynamicSharedMemorySize, shmem_f);

    setup_kernel<<<2048, 256, 0, stream>>>(hGA, hGB, cnt, colpair, wpair, tags);
    input_scatter_kernel<<<N_IN, BATCH, 0, stream>>>(bin, x, in_w, in_idx,
                                                     biases, cnt);
    ell_build_kernel<<<(N_EDGES + 255) / 256, 256, 0, stream>>>(rows, cols, rec_w,
                                                                colpair, wpair, cnt);
    sort_kernel<<<N_NODES / NPB, NT, 0, stream>>>(cnt, permG, rankOf);
    reorder_kernel<<<dim3((N_NODES + 255) / 256, PAIRS), 256, 0, stream>>>(
        colpair, wpair, permG, rankOf, cwR);

    void* args[] = { (void*)&hGA, (void*)&hGB, (void*)&bin, (void*)&biases,
                     (void*)&cwR, (void*)&cnt, (void*)&permG, (void*)&tags };
    hipError_t ce = hipLaunchCooperativeKernel((void*)persistent_kernel,
                                               dim3(NBLK), dim3(NT),
                                               args, shmem_p, stream);
    const uint* hfinal;
    if (ce == hipSuccess) {
        hfinal = hGB;                 // t=149 (odd) wrote hGB
    } else {
        uint* pa = hGA;
        uint* pb = hGB;
        for (int t = 0; t < ITERS; t++) {
            step_kernel<<<NBLK, NT, shmem_f, stream>>>(pa, pb, bin, biases,
                                                       cwR, cnt, permG);
            uint* tmp = pa; pa = pb; pb = tmp;
        }
        hfinal = pa;                  // last write landed in the buffer now in pa
    }

    output_kernel<<<BATCH, N_OUT, 0, stream>>>(hfinal, oidx, rankOf, out_w, out);
}

// Round 19
// 1044.400 us; speedup vs baseline: 1.1578x; 1.1578x over previous
//
#include <hip/hip_runtime.h>
#include <hip/hip_fp16.h>

#define N_NODES 20000
#define N_EDGES 320000
#define BATCH   64
#define N_IN    128
#define N_OUT   256
#define CAP     64
#define ITERS   150
#define LEAK    0.01f

#define CNT_MASK 0x3FFFFFFF
#define FLAG_BIT (1 << 30)

#define NSLICE 32          // batch pairs; slice s owns batch elems {2s,2s+1}
#define BPS    8           // blocks per slice
#define NPB    2500        // ranks per block-chunk
#define NT     1024        // threads per block
#define NBLK   (NSLICE * BPS)
#define SLICE_U32 20480    // padded slice stride (u32)
#define OWN_U128  625      // NPB/4 uint4 per sub-block
#define PAIRS  32          // edge-pair slots per node (CAP/2)
#define TAG_STRIDE 32      // uints -> 128 B between tags

typedef unsigned int uint;
typedef unsigned long long ull;
typedef _Float16 h2_t __attribute__((ext_vector_type(2)));
typedef uint u32x4 __attribute__((ext_vector_type(4)));

// MALL-coherent accessors — RELAXED sc0 sc1 ONLY (L1+L2 bypass; Infinity-
// Cache-coherent). Proven protocol (r9/10/11/14/15/17). acquire/release
// (whole-L2 inv/wb) and the XCD-L2 exchange path (hangs r13/r16) are banned.
// Publish MUST be 16B-per-lane contiguous from LDS staging (r18 lesson:
// register-publish at stride-12 = 3x write amplification).
__device__ __forceinline__ void st128_mall(u32x4* p, u32x4 v) {
    asm volatile("global_store_dwordx4 %0, %1, off sc0 sc1"
                 :: "v"(p), "v"(v) : "memory");
}
__device__ __forceinline__ void st32_mall(uint* p, uint v) {
    asm volatile("global_store_dword %0, %1, off sc0 sc1"
                 :: "v"(p), "v"(v) : "memory");
}
__device__ __forceinline__ uint ld32_mall(const uint* p) {
    uint v;
    asm volatile("global_load_dword %0, %1, off sc0 sc1\n\t"
                 "s_waitcnt vmcnt(0)"
                 : "=v"(v) : "v"(p) : "memory");
    return v;
}

__device__ __forceinline__ float fdot2u(uint w, uint h, float acc) {
    union { uint u; h2_t h; } a, b; a.u = w; b.u = h;
    return __builtin_amdgcn_fdot2(a.h, b.h, acc, false);
}

// ---------------------------------------------------------------------------
// setup: zero both h buffers (incl. padding), cnt, meta, tags
// ---------------------------------------------------------------------------
__global__ void setup_kernel(uint* __restrict__ hGA, uint* __restrict__ hGB,
                             int* __restrict__ cnt,
                             uint* __restrict__ colpair, uint* __restrict__ wpair,
                             uint* __restrict__ tags) {
    int idx = blockIdx.x * blockDim.x + threadIdx.x;
    int stride = gridDim.x * blockDim.x;
    for (int i = idx; i < NSLICE * SLICE_U32; i += stride) { hGA[i] = 0u; hGB[i] = 0u; }
    for (int i = idx; i < N_NODES; i += stride) cnt[i] = 0;
    for (int i = idx; i < PAIRS * N_NODES; i += stride) { colpair[i] = 0u; wpair[i] = 0u; }
    for (int i = idx; i < NSLICE * BPS * TAG_STRIDE; i += stride) tags[i] = 0u;
}

// ---------------------------------------------------------------------------
// input scatter: bin[in_idx[i]][b] = bias + in_w[i]*x[b][i], last-wins.
// Flags the node (bit 30 of cnt).
// ---------------------------------------------------------------------------
__global__ void input_scatter_kernel(float* __restrict__ bin,
                                     const float* __restrict__ x,
                                     const float* __restrict__ in_w,
                                     const int* __restrict__ in_idx,
                                     const float* __restrict__ biases,
                                     int* __restrict__ cnt) {
    int i = blockIdx.x;
    int b = threadIdx.x;
    int node = in_idx[i];
    if (b == 0) atomicOr(&cnt[node], FLAG_BIT);
    for (int j = i + 1; j < N_IN; j++)
        if (in_idx[j] == node) return;
    bin[node * BATCH + b] = biases[node] + in_w[i] * x[b * N_IN + i];
}

// ---------------------------------------------------------------------------
// COO -> paired transposed ELL in NODE space (atomicOr into 16-bit subwords)
// ---------------------------------------------------------------------------
__global__ void ell_build_kernel(const int* __restrict__ rows,
                                 const int* __restrict__ cols,
                                 const float* __restrict__ rec_w,
                                 uint* __restrict__ colpair, uint* __restrict__ wpair,
                                 int* __restrict__ cnt) {
    int e = blockIdx.x * blockDim.x + threadIdx.x;
    if (e >= N_EDGES) return;
    int r = rows[e];
    int s = atomicAdd(&cnt[r], 1) & CNT_MASK;
    if (s < CAP) {
        int p = s >> 1, sh = (s & 1) * 16;
        atomicOr(&colpair[(size_t)p * N_NODES + r], (uint)cols[e] << sh);
        uint hw = (uint)__half_as_ushort(__float2half(rec_w[e]));
        atomicOr(&wpair[(size_t)p * N_NODES + r], hw << sh);
    }
}

// ---------------------------------------------------------------------------
// per-chunk descending counting sort by degree.
// ---------------------------------------------------------------------------
__global__ __launch_bounds__(NT) void sort_kernel(const int* __restrict__ cnt,
                                                  int* __restrict__ permG,
                                                  int* __restrict__ rankOf) {
    __shared__ int hist[65], off[65];
    int nbase = blockIdx.x * NPB;
    int tid = threadIdx.x;
    if (tid < 65) hist[tid] = 0;
    __syncthreads();
    for (int r = tid; r < NPB; r += NT) {
        int c = cnt[nbase + r] & CNT_MASK; if (c > CAP) c = CAP;
        atomicAdd(&hist[c], 1);
    }
    __syncthreads();
    if (tid == 0) {
        int run = 0;
        for (int c = CAP; c >= 0; c--) { off[c] = run; run += hist[c]; }
    }
    __syncthreads();
    for (int r = tid; r < NPB; r += NT) {
        int c = cnt[nbase + r] & CNT_MASK; if (c > CAP) c = CAP;
        int rk = atomicAdd(&off[c], 1);
        permG[nbase + rk] = nbase + r;
        rankOf[nbase + r] = nbase + rk;
    }
}

// reorder meta into RANK space, remap columns, merge into one uint2
__global__ void reorder_kernel(const uint* __restrict__ colpair,
                               const uint* __restrict__ wpair,
                               const int* __restrict__ permG,
                               const int* __restrict__ rankOf,
                               uint2* __restrict__ cwR) {
    int r = blockIdx.x * blockDim.x + threadIdx.x;
    int p = blockIdx.y;
    if (r >= N_NODES) return;
    size_t o = (size_t)p * N_NODES;
    int n = permG[r];
    uint cc = colpair[o + n];
    uint lo = (uint)rankOf[cc & 0xFFFFu];
    uint hi = (uint)rankOf[cc >> 16];
    cwR[o + r] = make_uint2(lo | (hi << 16), wpair[o + n]);
}

// ---------------------------------------------------------------------------
// shared pieces
// ---------------------------------------------------------------------------
__device__ __forceinline__ uint finish_node(float a0, float a1, float b0, float b1) {
    float r0 = b0 + a0, r1 = b1 + a1;
    float u0 = (r0 < 0.f) ? r0 * LEAK : r0;
    float u1 = (r1 < 0.f) ? r1 * LEAK : r1;
    float v0 = (u0 > 0.5f) ? (1.0f - 0.25f / u0) : u0;
    float v1 = (u1 > 0.5f) ? (1.0f - 0.25f / u1) : u1;
    union { __half2 h; uint u; } p;
    p.h = __halves2half2(__float2half(v0), __float2half(v1));
    return p.u;
}

__device__ __forceinline__ void hoist_consts(
        int nbase, int tid, int s,
        const int* __restrict__ cnt, const int* __restrict__ permG,
        const float* __restrict__ bin, const float* __restrict__ biases,
        int* rank, float* mb0, float* mb1, bool* ma, int& kp) {
    int kmax = 0;
#pragma unroll
    for (int j = 0; j < 3; j++) {
        int sl = 3 * tid + j;
        ma[j] = (sl < NPB);
        rank[j] = nbase + (ma[j] ? sl : 0);
        int n = permG[rank[j]];
        int cv = cnt[n];
        int c = cv & CNT_MASK; if (c > CAP) c = CAP;
        if (ma[j] && c > kmax) kmax = c;
        if (cv & FLAG_BIT) {
            mb0[j] = bin[(size_t)n * BATCH + 2 * s];
            mb1[j] = bin[(size_t)n * BATCH + 2 * s + 1];
        } else {
            float bb = biases[n]; mb0[j] = bb; mb1[j] = bb;
        }
    }
    kp = (kmax + 1) >> 1;
}

// 3 rank streams x paired edges: 6 independent ds_reads/iter, fdot2 accum.
__device__ __forceinline__ void compute_pairs(
        const int* rank, int kp,
        const uint2* __restrict__ cwR,
        const uint* __restrict__ lds_h, float* a0, float* a1) {
    a0[0] = a0[1] = a0[2] = 0.f;
    a1[0] = a1[1] = a1[2] = 0.f;
#pragma unroll 2
    for (int p = 0; p < kp; p++) {
        size_t o = (size_t)p * N_NODES;
#pragma unroll
        for (int j = 0; j < 3; j++) {
            uint2 m = cwR[o + rank[j]];
            uint ha = lds_h[m.x & 0xFFFFu];
            uint hb = lds_h[m.x >> 16];
            uint lo = __builtin_amdgcn_perm(hb, ha, 0x05040100u);
            uint hi = __builtin_amdgcn_perm(hb, ha, 0x07060302u);
            a0[j] = fdot2u(m.y, lo, a0[j]);
            a1[j] = fdot2u(m.y, hi, a1[j]);
        }
    }
}

// ---------------------------------------------------------------------------
// persistent kernel: DOUBLE-BUFFERED LDS (2 x 80 KB) + LDS-STAGED publish.
// Per step (3 barriers):
//   compute from cur -> own ds_write to nxt (different buffer: no barrier)
//   -> sync1 (own writes visible, cur reads done)
//   -> publish own range from nxt: tid<625 x 16B sc0sc1 (coalesced, r17-
//      proven; NOT register-publish — r18's 3x write amplification)
//   -> sync2 (publish drained) -> tid0 writes tag (monotone, single-writer)
//      while waves 0..13 poll remote tags and refresh nxt's remote ranges
//   -> sync3 -> swap(cur,nxt).
// ---------------------------------------------------------------------------
__global__ __launch_bounds__(NT) void persistent_kernel(
        uint* hGA, uint* hGB,
        const float* __restrict__ bin, const float* __restrict__ biases,
        const uint2* __restrict__ cwR,
        const int* __restrict__ cnt, const int* __restrict__ permG,
        uint* tags) {
    extern __shared__ uint lds_all[];        // 2 x SLICE_U32 = 160 KB
    uint* bufA = lds_all;
    uint* bufB = lds_all + SLICE_U32;
    int bid = blockIdx.x, tid = threadIdx.x;
    int s = bid >> 3, sub = bid & 7;
    int nbase = sub * NPB;
    const int wave = tid >> 6, lane = tid & 63;

    int rank[3]; float mb0[3], mb1[3]; bool ma[3]; int kp;
    hoist_consts(nbase, tid, s, cnt, permG, bin, biases, rank, mb0, mb1, ma, kp);

    for (int i = tid; i < SLICE_U32; i += NT) bufA[i] = 0u;   // h_{-1} = 0
    __syncthreads();

    uint* hA_s = hGA + (size_t)s * SLICE_U32;
    uint* hB_s = hGB + (size_t)s * SLICE_U32;
    uint* mytag = &tags[(s * BPS + sub) * TAG_STRIDE];

    uint* cur = bufA;
    uint* nxt = bufB;

    for (int t = 0; t < ITERS; t++) {
        uint* hout = (t & 1) ? hB_s : hA_s;

        float a0[3], a1[3];
        compute_pairs(rank, kp, cwR, cur, a0, a1);
        // own-write to nxt (race-free: compute reads cur)
#pragma unroll
        for (int j = 0; j < 3; j++)
            if (ma[j]) nxt[rank[j]] = finish_node(a0[j], a1[j], mb0[j], mb1[j]);

        __syncthreads();            // own writes visible; cur reads done
        // publish own range coalesced from nxt (625 x 16B sc0sc1)
        if (tid < OWN_U128) {
            int i = sub * OWN_U128 + tid;
            st128_mall((u32x4*)hout + i, ((const u32x4*)nxt)[i]);
        }
        if (t == ITERS - 1) break;

        __syncthreads();            // publish drained (vmcnt0 @ barrier)
        if (tid == 0) st32_mall(mytag, (uint)(t + 1));

        // refresh nxt's remote sub-ranges (waves 0..13; 2 waves per range)
        if (wave < 14) {
            int sb_idx = wave >> 1;
            int sb = sb_idx + (sb_idx >= sub ? 1 : 0);
            int half = wave & 1;
            if (lane == 0) {
                const uint* rt = &tags[(s * BPS + sb) * TAG_STRIDE];
                while (ld32_mall(rt) < (uint)(t + 1)) __builtin_amdgcn_s_sleep(2);
            }
            // wave reconverged: 2 waves cover this sub-range's 625 uint4
            const u32x4* sp = (const u32x4*)hout + sb * OWN_U128;
            u32x4* dp = (u32x4*)nxt + sb * OWN_U128;
            int it0 = half * 64 + lane;          // 0..127
            int it4 = it0 + 512;                 // 512..639 (guard > 624)
            int c4 = (it4 <= 624) ? it4 : 624;
            u32x4 r0, r1, r2, r3, r4;
            asm volatile(
                "global_load_dwordx4 %0, %5, off sc0 sc1\n\t"
                "global_load_dwordx4 %1, %6, off sc0 sc1\n\t"
                "global_load_dwordx4 %2, %7, off sc0 sc1\n\t"
                "global_load_dwordx4 %3, %8, off sc0 sc1\n\t"
                "global_load_dwordx4 %4, %9, off sc0 sc1\n\t"
                "s_waitcnt vmcnt(0)"
                : "=&v"(r0), "=&v"(r1), "=&v"(r2), "=&v"(r3), "=&v"(r4)
                : "v"(sp + it0), "v"(sp + it0 + 128), "v"(sp + it0 + 256),
                  "v"(sp + it0 + 384), "v"(sp + c4)
                : "memory");
            dp[it0] = r0; dp[it0 + 128] = r1; dp[it0 + 256] = r2;
            dp[it0 + 384] = r3;
            if (it4 <= 624) dp[it4] = r4;
        }
        __syncthreads();            // refresh + own-writes visible
        uint* tmp = cur; cur = nxt; nxt = tmp;
    }
}

// ---------------------------------------------------------------------------
// fallback: one step per launch (dispatch boundary = sync), 80 KB LDS,
// byte-identical numerics (r17-proven)
// ---------------------------------------------------------------------------
__global__ __launch_bounds__(NT) void step_kernel(
        const uint* __restrict__ hprev, uint* __restrict__ hnext,
        const float* __restrict__ bin, const float* __restrict__ biases,
        const uint2* __restrict__ cwR,
        const int* __restrict__ cnt, const int* __restrict__ permG) {
    extern __shared__ uint lds_h[];
    int bid = blockIdx.x, tid = threadIdx.x;
    int s = bid >> 3, sub = bid & 7;
    int nbase = sub * NPB;

    int rank[3]; float mb0[3], mb1[3]; bool ma[3]; int kp;
    hoist_consts(nbase, tid, s, cnt, permG, bin, biases, rank, mb0, mb1, ma, kp);

    const uint* hp = hprev + (size_t)s * SLICE_U32;
    for (int i = tid; i < SLICE_U32; i += NT) lds_h[i] = hp[i];
    __syncthreads();

    float a0[3], a1[3];
    compute_pairs(rank, kp, cwR, lds_h, a0, a1);
    uint* ho = hnext + (size_t)s * SLICE_U32;
#pragma unroll
    for (int j = 0; j < 3; j++)
        if (ma[j]) ho[rank[j]] = finish_node(a0[j], a1[j], mb0[j], mb1[j]);
}

// ---------------------------------------------------------------------------
// output gather: out[b][o] = out_w[o] * h[rankOf[out_idx[o]]][b]
// ---------------------------------------------------------------------------
__global__ void output_kernel(const uint* __restrict__ hfinal,
                              const int* __restrict__ out_idx,
                              const int* __restrict__ rankOf,
                              const float* __restrict__ out_w,
                              float* __restrict__ out) {
    int o = threadIdx.x;
    int b = blockIdx.x;
    uint v = hfinal[(size_t)(b >> 1) * SLICE_U32 + rankOf[out_idx[o]]];
    unsigned short h = (b & 1) ? (unsigned short)(v >> 16) : (unsigned short)(v & 0xFFFF);
    out[b * N_OUT + o] = out_w[o] * __half2float(__ushort_as_half(h));
}

// ---------------------------------------------------------------------------
extern "C" void kernel_launch(void* const* d_in, const int* in_sizes, int n_in,
                              void* d_out, int out_size, void* d_ws, size_t ws_size,
                              hipStream_t stream) {
    const float* x      = (const float*)d_in[0];
    const float* in_w   = (const float*)d_in[1];
    const float* out_w  = (const float*)d_in[2];
    const float* rec_w  = (const float*)d_in[3];
    const float* biases = (const float*)d_in[4];
    const int*   rows   = (const int*)d_in[5];
    const int*   cols   = (const int*)d_in[6];
    const int*   in_idx = (const int*)d_in[7];
    const int*   oidx   = (const int*)d_in[8];
    float* out = (float*)d_out;

    char* ws = (char*)d_ws;
    uint*  hGA     = (uint*)ws;  ws += (size_t)NSLICE * SLICE_U32 * 4;  // 2.62 MB
    uint*  hGB     = (uint*)ws;  ws += (size_t)NSLICE * SLICE_U32 * 4;  // 2.62 MB
    float* bin     = (float*)ws; ws += (size_t)N_NODES * BATCH * 4;     // 5.12 MB
    uint*  colpair = (uint*)ws;  ws += (size_t)PAIRS * N_NODES * 4;     // 2.56 MB
    uint*  wpair   = (uint*)ws;  ws += (size_t)PAIRS * N_NODES * 4;     // 2.56 MB
    uint2* cwR     = (uint2*)ws; ws += (size_t)PAIRS * N_NODES * 8;     // 5.12 MB
    int*   cnt     = (int*)ws;   ws += (size_t)N_NODES * 4;             // 80 KB
    int*   permG   = (int*)ws;   ws += (size_t)N_NODES * 4;             // 80 KB
    int*   rankOf  = (int*)ws;   ws += (size_t)N_NODES * 4;             // 80 KB
    uint*  tags    = (uint*)ws;  ws += (size_t)NSLICE * BPS * TAG_STRIDE * 4;

    const int shmem_p = 2 * SLICE_U32 * 4;   // 163840 B (full CU LDS)
    const int shmem_f = SLICE_U32 * 4;       // 81920 B (fallback)
    hipFuncSetAttribute((const void*)persistent_kernel,
                        hipFuncAttributeMaxDynamicSharedMemorySize, shmem_p);
    hipFuncSetAttribute((const void*)step_kernel,
                        hipFuncAttributeMaxDynamicSharedMemorySize, shmem_f);

    setup_kernel<<<2048, 256, 0, stream>>>(hGA, hGB, cnt, colpair, wpair, tags);
    input_scatter_kernel<<<N_IN, BATCH, 0, stream>>>(bin, x, in_w, in_idx,
                                                     biases, cnt);
    ell_build_kernel<<<(N_EDGES + 255) / 256, 256, 0, stream>>>(rows, cols, rec_w,
                                                                colpair, wpair, cnt);
    sort_kernel<<<N_NODES / NPB, NT, 0, stream>>>(cnt, permG, rankOf);
    reorder_kernel<<<dim3((N_NODES + 255) / 256, PAIRS), 256, 0, stream>>>(
        colpair, wpair, permG, rankOf, cwR);

    void* args[] = { (void*)&hGA, (void*)&hGB, (void*)&bin, (void*)&biases,
                     (void*)&cwR, (void*)&cnt, (void*)&permG, (void*)&tags };
    hipError_t ce = hipLaunchCooperativeKernel((void*)persistent_kernel,
                                               dim3(NBLK), dim3(NT),
                                               args, shmem_p, stream);
    const uint* hfinal;
    if (ce == hipSuccess) {
        hfinal = hGB;                 // t=149 (odd) wrote hGB
    } else {
        uint* pa = hGA;
        uint* pb = hGB;
        for (int t = 0; t < ITERS; t++) {
            step_kernel<<<NBLK, NT, shmem_f, stream>>>(pa, pb, bin, biases,
                                                       cwR, cnt, permG);
            uint* tmp = pa; pa = pb; pb = tmp;
        }
        hfinal = pa;                  // last write landed in the buffer now in pa
    }

    output_kernel<<<BATCH, N_OUT, 0, stream>>>(hfinal, oidx, rankOf, out_w, out);
}